// Round 1
// baseline (361.896 us; speedup 1.0000x reference)
//
#include <hip/hip_runtime.h>
#include <stdint.h>
#include <stddef.h>

#define BATCH 32
#define NPIX  1024
#define DHID  128
#define CINCH 256
#define KVT   64

typedef __bf16 bf16;
typedef __attribute__((ext_vector_type(4))) __bf16 bf16x4;
typedef __attribute__((ext_vector_type(8))) __bf16 bf16x8;
typedef __attribute__((ext_vector_type(4))) float f32x4;
typedef __attribute__((ext_vector_type(4))) unsigned int u32x4;

#define MFMA16(a,b,c) __builtin_amdgcn_mfma_f32_16x16x32_bf16((a),(b),(c),0,0,0)

__device__ __forceinline__ void split_bf16(float x, bf16& h, bf16& l) {
  h = (bf16)x;
  l = (bf16)(x - (float)h);
}

// ---------------------------------------------------------------------------
// Kernel 0: split Wq/Wk (fp32 [128][256]) into hi/lo bf16 arrays.
// ---------------------------------------------------------------------------
__global__ void wsplit_kernel(const float* __restrict__ Wq, const float* __restrict__ Wk,
                              bf16* __restrict__ WqHi, bf16* __restrict__ WqLo,
                              bf16* __restrict__ WkHi, bf16* __restrict__ WkLo) {
  int i = blockIdx.x * blockDim.x + threadIdx.x;
  if (i < DHID * CINCH) {
    bf16 h, l;
    split_bf16(Wq[i], h, l); WqHi[i] = h; WqLo[i] = l;
    split_bf16(Wk[i], h, l); WkHi[i] = h; WkLo[i] = l;
  }
}

// ---------------------------------------------------------------------------
// Kernel 1: fused projection (split-bf16 MFMA, 3 passes) + left->out copy +
// V bf16 conversion. One wave per (16-pixel tile, batch, Q-or-K).
// Output stored transposed: QT/KT [b][p][d] as hi/lo bf16.
// A = W (row=d, k=c), B = X (k=c, col=p). D: row = 4*(l>>4)+r, col = l&15.
// ---------------------------------------------------------------------------
__global__ __launch_bounds__(64) void proj_kernel(
    const float* __restrict__ Xl, const float* __restrict__ Xr,
    const bf16* __restrict__ WqHi, const bf16* __restrict__ WqLo,
    const bf16* __restrict__ WkHi, const bf16* __restrict__ WkLo,
    const float* __restrict__ bq,  const float* __restrict__ bk,
    bf16* __restrict__ QThi, bf16* __restrict__ QTlo,
    bf16* __restrict__ KThi, bf16* __restrict__ KTlo,
    float* __restrict__ out, bf16* __restrict__ Vb)
{
  const int lane = threadIdx.x;
  const int g    = lane >> 4;
  const int r16  = lane & 15;
  const int p0   = blockIdx.x * 16;
  const int b    = blockIdx.y;
  const bool isK = (blockIdx.z != 0);

  const float* X    = (isK ? Xr : Xl) + (size_t)b * CINCH * NPIX;
  const bf16*  Whi  = isK ? WkHi : WqHi;
  const bf16*  Wlo  = isK ? WkLo : WqLo;
  const float* bias = isK ? bk : bq;
  bf16* outHi = isK ? KThi : QThi;
  bf16* outLo = isK ? KTlo : QTlo;

  f32x4 acc[8];
#pragma unroll
  for (int i = 0; i < 8; ++i) acc[i] = (f32x4){0.f, 0.f, 0.f, 0.f};

  const int p = p0 + r16;

  for (int c0 = 0; c0 < CINCH; c0 += 32) {
    // B-fragment from X: lane holds X[c0+8g+j][p], j=0..7, split hi/lo.
    bf16x8 xh, xl;
#pragma unroll
    for (int j = 0; j < 8; ++j) {
      int c = c0 + 8 * g + j;
      float x = X[(size_t)c * NPIX + p];
      // fused side outputs (each (c,p) visited exactly once per z)
      if (!isK) out[((size_t)b * 512 + c) * NPIX + p] = x;
      else      Vb[((size_t)b * CINCH + c) * NPIX + p] = (bf16)x;
      bf16 h, l; split_bf16(x, h, l);
      xh[j] = h; xl[j] = l;
    }
#pragma unroll
    for (int dt = 0; dt < 8; ++dt) {
      const bf16* wh = Whi + (size_t)(dt * 16 + r16) * CINCH + c0 + 8 * g;
      const bf16* wl = Wlo + (size_t)(dt * 16 + r16) * CINCH + c0 + 8 * g;
      bf16x8 fwh = *(const bf16x8*)wh;
      bf16x8 fwl = *(const bf16x8*)wl;
      acc[dt] = MFMA16(fwh, xh, acc[dt]);
      acc[dt] = MFMA16(fwh, xl, acc[dt]);
      acc[dt] = MFMA16(fwl, xh, acc[dt]);
    }
  }

  // Epilogue: add bias, split to hi/lo, store transposed [b][p][d].
#pragma unroll
  for (int dt = 0; dt < 8; ++dt) {
    bf16x4 vh, vl;
#pragma unroll
    for (int r = 0; r < 4; ++r) {
      int d = dt * 16 + 4 * g + r;
      float v = acc[dt][r] + bias[d];
      bf16 h, l; split_bf16(v, h, l);
      vh[r] = h; vl[r] = l;
    }
    size_t off = ((size_t)b * NPIX + p) * DHID + dt * 16 + 4 * g;
    *(bf16x4*)(outHi + off) = vh;
    *(bf16x4*)(outLo + off) = vl;
  }
}

// ---------------------------------------------------------------------------
// Kernel 2: flash attention. 256 WGs (b = blockIdx&31 -> XCD = b%8), 8 waves,
// each wave owns 16 queries. Swapped QK: S^T[p][q] = sum_d K[d,p] Q[d,q],
// so per-lane q = lane&15 is fixed and softmax stats are lane-local.
// K tile staged in LDS (XOR-swizzled, conflict-free); V read from global.
// ---------------------------------------------------------------------------
__global__ __launch_bounds__(512, 2) void attn_kernel(
    const bf16* __restrict__ QThi, const bf16* __restrict__ QTlo,
    const bf16* __restrict__ KThi, const bf16* __restrict__ KTlo,
    const bf16* __restrict__ Vb,   float* __restrict__ out)
{
  __shared__ bf16 sKh[KVT * DHID];   // 16 KB, swizzled
  __shared__ bf16 sKl[KVT * DHID];   // 16 KB, swizzled
  __shared__ bf16 sP [8 * KVT * 16]; // 16 KB, per-wave P tiles [p][q]

  const int tid  = threadIdx.x;
  const int wave = tid >> 6;
  const int lane = tid & 63;
  const int g    = lane >> 4;
  const int r16  = lane & 15;
  const int b    = blockIdx.x & 31;
  const int qt   = blockIdx.x >> 5;
  const int q0   = qt * 128 + wave * 16;

  // Q fragments (B operand): lane holds QT[q0+r16][32*kk + 8*g + j]
  const bf16* qbh = QThi + ((size_t)b * NPIX + q0 + r16) * DHID + 8 * g;
  const bf16* qbl = QTlo + ((size_t)b * NPIX + q0 + r16) * DHID + 8 * g;
  bf16x8 qfh[4], qfl[4];
#pragma unroll
  for (int kk = 0; kk < 4; ++kk) {
    qfh[kk] = *(const bf16x8*)(qbh + 32 * kk);
    qfl[kk] = *(const bf16x8*)(qbl + 32 * kk);
  }

  const bf16* khB = KThi + (size_t)b * NPIX * DHID;
  const bf16* klB = KTlo + (size_t)b * NPIX * DHID;
  const bf16* vB  = Vb   + (size_t)b * CINCH * NPIX;

  u32x4 stKh[2], stKl[2];

  auto issue_loads = [&](int kt) {
#pragma unroll
    for (int i = 0; i < 2; ++i) {
      int chunk = tid + i * 512;            // 0..1023 : 64 rows x 16 chunks
      int row = chunk >> 4, cc = chunk & 15;
      stKh[i] = *(const u32x4*)(khB + (size_t)(kt + row) * DHID + cc * 8);
      stKl[i] = *(const u32x4*)(klB + (size_t)(kt + row) * DHID + cc * 8);
    }
  };
  auto write_lds = [&]() {
#pragma unroll
    for (int i = 0; i < 2; ++i) {
      int chunk = tid + i * 512;
      int row = chunk >> 4, cc = chunk & 15;
      int boff = row * 256 + ((cc * 16) ^ ((row & 7) * 16));
      *(u32x4*)((char*)sKh + boff) = stKh[i];
      *(u32x4*)((char*)sKl + boff) = stKl[i];
    }
  };

  f32x4 oacc[16];
#pragma unroll
  for (int i = 0; i < 16; ++i) oacc[i] = (f32x4){0.f, 0.f, 0.f, 0.f};
  float mrun = -1e30f, lrun = 0.f;

  issue_loads(0);
  write_lds();
  __syncthreads();

  for (int t = 0; t < 16; ++t) {
    if (t < 15) issue_loads((t + 1) * KVT);   // prefetch next K tile (T14)
    const int kt = t * KVT;

    // --- QK^T (split-bf16, 3 MFMAs per frag pair) -> S^T[p_local][q] ---
    f32x4 sacc[4];
#pragma unroll
    for (int pt = 0; pt < 4; ++pt) sacc[pt] = (f32x4){0.f, 0.f, 0.f, 0.f};
#pragma unroll
    for (int pt = 0; pt < 4; ++pt) {
      int row = pt * 16 + r16;
      int rsw = (row & 7) * 16;
#pragma unroll
      for (int kk = 0; kk < 4; ++kk) {
        int boff = row * 256 + ((64 * kk + 16 * g) ^ rsw);
        bf16x8 kfh = *(const bf16x8*)((const char*)sKh + boff);
        bf16x8 kfl = *(const bf16x8*)((const char*)sKl + boff);
        sacc[pt] = MFMA16(kfh, qfh[kk], sacc[pt]);
        sacc[pt] = MFMA16(kfh, qfl[kk], sacc[pt]);
        sacc[pt] = MFMA16(kfl, qfh[kk], sacc[pt]);
      }
    }

    // --- online softmax over this 64-key tile; per lane q = q0+r16 ---
    float pmax = sacc[0][0];
#pragma unroll
    for (int pt = 0; pt < 4; ++pt)
#pragma unroll
      for (int r = 0; r < 4; ++r) pmax = fmaxf(pmax, sacc[pt][r]);
    pmax = fmaxf(pmax, __shfl_xor(pmax, 16));
    pmax = fmaxf(pmax, __shfl_xor(pmax, 32));
    float mnew  = fmaxf(mrun, pmax);
    float scale = __expf(mrun - mnew);
    float psum = 0.f;
    bf16* sPw = sP + wave * (KVT * 16);
#pragma unroll
    for (int pt = 0; pt < 4; ++pt)
#pragma unroll
      for (int r = 0; r < 4; ++r) {
        float pe = __expf(sacc[pt][r] - mnew);
        psum += pe;
        sPw[(16 * pt + 4 * g + r) * 16 + r16] = (bf16)pe;  // P^T[p][q]
      }
    psum += __shfl_xor(psum, 16);
    psum += __shfl_xor(psum, 32);
    lrun = lrun * scale + psum;
    mrun = mnew;
    if (__any(scale < 1.f)) {
#pragma unroll
      for (int i = 0; i < 16; ++i) {
        oacc[i][0] *= scale; oacc[i][1] *= scale;
        oacc[i][2] *= scale; oacc[i][3] *= scale;
      }
    }

    // --- PV: O[c][q] += V[c,p] * P^T[p][q] ---
    bf16x8 pf[2];
#pragma unroll
    for (int kk2 = 0; kk2 < 2; ++kk2)
#pragma unroll
      for (int j = 0; j < 8; ++j)
        pf[kk2][j] = sPw[(32 * kk2 + 8 * g + j) * 16 + r16];

#pragma unroll
    for (int ct = 0; ct < 16; ++ct) {
      int c = ct * 16 + r16;
#pragma unroll
      for (int kk2 = 0; kk2 < 2; ++kk2) {
        bf16x8 vf = *(const bf16x8*)(vB + (size_t)c * NPIX + kt + 32 * kk2 + 8 * g);
        oacc[ct] = MFMA16(vf, pf[kk2], oacc[ct]);
      }
    }

    __syncthreads();
    if (t < 15) { write_lds(); __syncthreads(); }
  }

  // --- epilogue: normalize, store attended to out[b][256+c][q] ---
  float inv = 1.f / lrun;
  float* outB = out + ((size_t)b * 512 + 256) * NPIX + q0 + r16;
#pragma unroll
  for (int ct = 0; ct < 16; ++ct)
#pragma unroll
    for (int r = 0; r < 4; ++r) {
      int c = ct * 16 + 4 * g + r;
      outB[(size_t)c * NPIX] = oacc[ct][r] * inv;
    }
}

// ---------------------------------------------------------------------------
extern "C" void kernel_launch(void* const* d_in, const int* in_sizes, int n_in,
                              void* d_out, int out_size, void* d_ws, size_t ws_size,
                              hipStream_t stream) {
  const float* left  = (const float*)d_in[0];
  const float* right = (const float*)d_in[1];
  const float* Wq    = (const float*)d_in[2];
  const float* bq    = (const float*)d_in[3];
  const float* Wk    = (const float*)d_in[4];
  const float* bk    = (const float*)d_in[5];
  float* out = (float*)d_out;
  char*  ws  = (char*)d_ws;

  bf16* WqHi = (bf16*)(ws);
  bf16* WqLo = (bf16*)(ws + 65536);
  bf16* WkHi = (bf16*)(ws + 131072);
  bf16* WkLo = (bf16*)(ws + 196608);
  size_t off = 262144;
  const size_t QSZ = (size_t)BATCH * NPIX * DHID * sizeof(bf16);  // 8 MB
  bf16* QThi = (bf16*)(ws + off); off += QSZ;
  bf16* QTlo = (bf16*)(ws + off); off += QSZ;
  bf16* KThi = (bf16*)(ws + off); off += QSZ;
  bf16* KTlo = (bf16*)(ws + off); off += QSZ;
  bf16* Vb   = (bf16*)(ws + off); off += (size_t)BATCH * CINCH * NPIX * sizeof(bf16);
  (void)ws_size; (void)in_sizes; (void)n_in; (void)out_size;

  wsplit_kernel<<<128, 256, 0, stream>>>(Wq, Wk, WqHi, WqLo, WkHi, WkLo);

  dim3 pgrid(64, 32, 2);
  proj_kernel<<<pgrid, 64, 0, stream>>>(left, right, WqHi, WqLo, WkHi, WkLo,
                                        bq, bk, QThi, QTlo, KThi, KTlo, out, Vb);

  attn_kernel<<<256, 512, 0, stream>>>(QThi, QTlo, KThi, KTlo, Vb, out);
}

// Round 2
// 235.434 us; speedup vs baseline: 1.5371x; 1.5371x over previous
//
#include <hip/hip_runtime.h>
#include <stdint.h>
#include <stddef.h>

#define NPIX  1024
#define DHID  128
#define CIN   256

typedef _Float16 f16;
typedef __attribute__((ext_vector_type(4))) _Float16 f16x4;
typedef __attribute__((ext_vector_type(8))) _Float16 f16x8;
typedef __attribute__((ext_vector_type(4))) float f32x4;
typedef __attribute__((ext_vector_type(16))) float f32x16;

#define MFMA16(a,b,c) __builtin_amdgcn_mfma_f32_16x16x32_f16((a),(b),(c),0,0,0)
#define MFMA32(a,b,c) __builtin_amdgcn_mfma_f32_32x32x16_f16((a),(b),(c),0,0,0)

typedef const __attribute__((address_space(1))) uint32_t GU32;
typedef __attribute__((address_space(3))) uint32_t LU32;

__device__ __forceinline__ void gll16(const void* g, void* l) {
  __builtin_amdgcn_global_load_lds((GU32*)g, (LU32*)l, 16, 0, 0);
}

// ---------------------------------------------------------------------------
// Kernel 0: W fp32 -> fp16
// ---------------------------------------------------------------------------
__global__ void wprep_kernel(const float* __restrict__ Wq, const float* __restrict__ Wk,
                             f16* __restrict__ Whq, f16* __restrict__ Whk) {
  int i = blockIdx.x * 256 + threadIdx.x;
  if (i < DHID * CIN) { Whq[i] = (f16)Wq[i]; Whk[i] = (f16)Wk[i]; }
}

// ---------------------------------------------------------------------------
// Kernel 1: projection (fp16 MFMA 16x16x32) + left->out copy + V fp16 cast.
// 256 threads = 4 waves; block = 64 pixels, full d=128, K=256 staged in LDS.
// ---------------------------------------------------------------------------
__global__ __launch_bounds__(256) void proj_kernel(
    const float* __restrict__ Xl, const float* __restrict__ Xr,
    const f16* __restrict__ Whq, const f16* __restrict__ Whk,
    const float* __restrict__ bq, const float* __restrict__ bk,
    f16* __restrict__ QT, f16* __restrict__ KT,
    float* __restrict__ out, f16* __restrict__ Vb)
{
  __shared__ f16 sX[32 * 68];    // c-chunk 32 x (64p), pitch 68 (pad)
  __shared__ f16 sO[64 * 136];   // epilogue transpose: 64p x 128d, pitch 136

  const int tid = threadIdx.x;
  const int w = tid >> 6, lane = tid & 63, g = lane >> 4, r16 = lane & 15;
  const int p0 = blockIdx.x * 64, b = blockIdx.y;
  const bool isK = (blockIdx.z != 0);

  const float* X = (isK ? Xr : Xl) + (size_t)b * CIN * NPIX;
  const f16* Wh = isK ? Whk : Whq;
  const float* bias = isK ? bk : bq;
  f16* QKT = (isK ? KT : QT) + (size_t)b * NPIX * DHID;

  f32x4 acc[8];
#pragma unroll
  for (int i = 0; i < 8; ++i)
#pragma unroll
    for (int j = 0; j < 4; ++j) acc[i][j] = 0.f;

  const int scl = tid >> 4;         // 0..15
  const int spl = (tid & 15) * 4;   // 0..60

  for (int c0 = 0; c0 < CIN; c0 += 32) {
    __syncthreads();
#pragma unroll
    for (int i = 0; i < 2; ++i) {
      int cl = scl + 16 * i;
      size_t goff = (size_t)(c0 + cl) * NPIX + p0 + spl;
      f32x4 v = *(const f32x4*)(X + goff);
      if (!isK) *(f32x4*)(out + ((size_t)b * 2 * CIN + c0 + cl) * NPIX + p0 + spl) = v;
      f16x4 hv = {(f16)v.x, (f16)v.y, (f16)v.z, (f16)v.w};
      if (isK) *(f16x4*)(Vb + (size_t)b * CIN * NPIX + goff) = hv;
      *(f16x4*)(&sX[cl * 68 + spl]) = hv;
    }
    __syncthreads();
    f16x8 xb;
#pragma unroll
    for (int j = 0; j < 8; ++j) xb[j] = sX[(8 * g + j) * 68 + 16 * w + r16];
#pragma unroll
    for (int dt = 0; dt < 8; ++dt) {
      f16x8 wa = *(const f16x8*)(Wh + (size_t)(dt * 16 + r16) * CIN + c0 + 8 * g);
      acc[dt] = MFMA16(wa, xb, acc[dt]);
    }
  }

  // epilogue: bias, fp16, transpose via LDS, coalesced 16B stores
#pragma unroll
  for (int dt = 0; dt < 8; ++dt) {
    f16x4 hv;
#pragma unroll
    for (int r = 0; r < 4; ++r) hv[r] = (f16)(acc[dt][r] + bias[dt * 16 + 4 * g + r]);
    *(f16x4*)(&sO[(16 * w + r16) * 136 + dt * 16 + 4 * g]) = hv;
  }
  __syncthreads();
  const int pr = tid >> 2, dseg = (tid & 3) * 32;
#pragma unroll
  for (int i = 0; i < 4; ++i) {
    f16x8 row = *(const f16x8*)(&sO[pr * 136 + dseg + 8 * i]);
    *(f16x8*)(QKT + (size_t)(p0 + pr) * DHID + dseg + 8 * i) = row;
  }
}

// ---------------------------------------------------------------------------
// Kernel 2: flash attention, fp16, 32x32x16 MFMA. 256 blocks x 256 thr
// (4 waves, 32 q each). K double-buffered in LDS via async global_load_lds
// with pre-swizzled source; V direct from global (L2); P via per-wave LDS.
// Swapped QK: S^T[p][q], softmax stats lane-local (q = lane&31).
// ---------------------------------------------------------------------------
__global__ __launch_bounds__(256) void attn_kernel(
    const f16* __restrict__ QT, const f16* __restrict__ KT,
    const f16* __restrict__ Vb, float* __restrict__ out)
{
  __shared__ f16 sK[2][64 * 128];  // 2 x 16 KB, XOR-swizzled rows
  __shared__ f16 sP[4][32 * 64];   // per-wave [q][p], 4 KB, swizzled

  const int tid = threadIdx.x;
  const int w = tid >> 6, lane = tid & 63;
  const int h = lane >> 5, l31 = lane & 31;
  const int b = blockIdx.x & 31, qt = blockIdx.x >> 5;
  const int q0 = qt * 128 + w * 32;

  const f16* QTb = QT + ((size_t)b * NPIX + q0 + l31) * DHID;
  const f16* KTb = KT + (size_t)b * NPIX * DHID;
  const f16* vBb = Vb + (size_t)b * CIN * NPIX;

  f16x8 qf[8];
#pragma unroll
  for (int kt = 0; kt < 8; ++kt) qf[kt] = *(const f16x8*)(QTb + 16 * kt + 8 * h);

  f32x16 oacc[8];
#pragma unroll
  for (int i = 0; i < 8; ++i)
#pragma unroll
    for (int j = 0; j < 16; ++j) oacc[i][j] = 0.f;

  float mrun = -3.0e38f, lrun = 0.f;
  const int swz = (l31 & 7) << 4;

  // stage K tile (64 rows x 128 d fp16 = 16 KB): linear LDS dest,
  // inverse-swizzled global source (chunk cc stored at byte (cc^(row&7))*16)
#define STAGE(kvt, buf)                                                        \
  {                                                                            \
    _Pragma("unroll")                                                          \
    for (int i = 0; i < 4; ++i) {                                              \
      int chunk = tid + 256 * i;                                               \
      int row = chunk >> 4, cc = chunk & 15;                                   \
      gll16(KTb + (size_t)((kvt) + row) * DHID + ((cc ^ (row & 7)) * 8),       \
            &sK[buf][chunk * 8]);                                              \
    }                                                                          \
  }

  STAGE(0, 0);
  __syncthreads();

  for (int t = 0; t < 16; ++t) {
    const int cur = t & 1;
    if (t < 15) STAGE((t + 1) * 64, cur ^ 1);

    // --- QK^T: S^T[64p][32q], 16 MFMA 32x32x16 ---
    f32x16 s0, s1;
#pragma unroll
    for (int j = 0; j < 16; ++j) { s0[j] = 0.f; s1[j] = 0.f; }
    const char* sKc = (const char*)&sK[cur][0];
#pragma unroll
    for (int kt = 0; kt < 8; ++kt) {
      int cb = 32 * kt + 16 * h;
      f16x8 k0 = *(const f16x8*)(sKc + l31 * 256 + (cb ^ swz));
      f16x8 k1 = *(const f16x8*)(sKc + (32 + l31) * 256 + (cb ^ swz));
      s0 = MFMA32(k0, qf[kt], s0);
      s1 = MFMA32(k1, qf[kt], s1);
    }

    // --- online softmax (lane-local q; rows split only across h) ---
    float pmax = -3.4e38f;
#pragma unroll
    for (int j = 0; j < 16; ++j) { pmax = fmaxf(pmax, s0[j]); pmax = fmaxf(pmax, s1[j]); }
    pmax = fmaxf(pmax, __shfl_xor(pmax, 32));
    if (__any(pmax > mrun + 8.f)) {        // defer-max (T13)
      float mnew = fmaxf(mrun, pmax);
      float sc = __expf(mrun - mnew);
      lrun *= sc; mrun = mnew;
#pragma unroll
      for (int i = 0; i < 8; ++i)
#pragma unroll
        for (int j = 0; j < 16; ++j) oacc[i][j] *= sc;
    }
    float psum = 0.f;
    char* sPw = (char*)&sP[w][0];
#pragma unroll
    for (int pt = 0; pt < 2; ++pt) {
#pragma unroll
      for (int rq = 0; rq < 4; ++rq) {
        const f32x16& s = pt ? s1 : s0;
        float e0 = __expf(s[4 * rq + 0] - mrun), e1 = __expf(s[4 * rq + 1] - mrun);
        float e2 = __expf(s[4 * rq + 2] - mrun), e3 = __expf(s[4 * rq + 3] - mrun);
        psum += e0 + e1 + e2 + e3;
        f16x4 p4 = {(f16)e0, (f16)e1, (f16)e2, (f16)e3};
        int p = 32 * pt + 8 * rq + 4 * h;    // C/D row map (m74)
        *(f16x4*)(sPw + l31 * 128 + ((p * 2) ^ swz)) = p4;
      }
    }
    psum += __shfl_xor(psum, 32);
    lrun += psum;

    // --- PV: O[256c][32q] += V[c][p] * P^T[p][q], 32 MFMA ---
    f16x8 pf[4];
#pragma unroll
    for (int pk = 0; pk < 4; ++pk)
      pf[pk] = *(const f16x8*)(sPw + l31 * 128 + (((16 * pk + 8 * h) * 2) ^ swz));
#pragma unroll
    for (int ct = 0; ct < 8; ++ct) {
      const f16* vrow = vBb + (size_t)(32 * ct + l31) * NPIX + t * 64 + 8 * h;
#pragma unroll
      for (int pk = 0; pk < 4; ++pk) {
        f16x8 vf = *(const f16x8*)(vrow + 16 * pk);
        oacc[ct] = MFMA32(vf, pf[pk], oacc[ct]);
      }
    }
    __syncthreads();   // drains vmcnt (staged tile t+1 complete) + sK safe to swap
  }

  // --- epilogue ---
  float inv = 1.f / lrun;
  float* ob = out + ((size_t)b * 2 * CIN + CIN) * NPIX + q0 + l31;
#pragma unroll
  for (int ct = 0; ct < 8; ++ct)
#pragma unroll
    for (int r = 0; r < 16; ++r) {
      int c = 32 * ct + (r & 3) + 8 * (r >> 2) + 4 * h;
      ob[(size_t)c * NPIX] = oacc[ct][r] * inv;
    }
}

// ---------------------------------------------------------------------------
extern "C" void kernel_launch(void* const* d_in, const int* in_sizes, int n_in,
                              void* d_out, int out_size, void* d_ws, size_t ws_size,
                              hipStream_t stream) {
  const float* left  = (const float*)d_in[0];
  const float* right = (const float*)d_in[1];
  const float* Wq    = (const float*)d_in[2];
  const float* bq    = (const float*)d_in[3];
  const float* Wk    = (const float*)d_in[4];
  const float* bk    = (const float*)d_in[5];
  float* out = (float*)d_out;
  char* ws = (char*)d_ws;

  f16* Whq = (f16*)(ws);
  f16* Whk = (f16*)(ws + 65536);
  size_t off = 131072;
  const size_t QSZ = (size_t)32 * NPIX * DHID * sizeof(f16);   // 8 MB
  f16* QT = (f16*)(ws + off); off += QSZ;
  f16* KT = (f16*)(ws + off); off += QSZ;
  f16* Vb = (f16*)(ws + off); off += (size_t)32 * CIN * NPIX * sizeof(f16);
  (void)ws_size; (void)in_sizes; (void)n_in; (void)out_size;

  wprep_kernel<<<128, 256, 0, stream>>>(Wq, Wk, Whq, Whk);

  dim3 pgrid(16, 32, 2);
  proj_kernel<<<pgrid, 256, 0, stream>>>(left, right, Whq, Whk, bq, bk,
                                         QT, KT, out, Vb);

  attn_kernel<<<256, 256, 0, stream>>>(QT, KT, Vb, out);
}